// Round 4
// baseline (127.351 us; speedup 1.0000x reference)
//
#include <hip/hip_runtime.h>
#include <math.h>

// src (8,3,512,512) f32 | grid1 (8,32,8,16,16) f32 | grid2 (8,27,8,16,16) f32
// out (8,3,512,512) f32
#define BATCH 8
#define IMH 512
#define IMW 512
#define HWSZ (IMH * IMW)
#define CH 32                  // channels per cell in transposed layout (grid2 padded)
#define CPADH 40               // LDS cell stride in halves (80 B: 16B-aligned, 20-bank stride)
#define L_CELLS (16 * 8)       // full row: 16 x-cells * 8 z
#define LSLOTH (L_CELLS * CPADH)   // 5120 halves = 10240 B per slab
#define ROWS 4                 // rows per block (software-pipelined)

typedef _Float16 h1;
typedef _Float16 h2 __attribute__((ext_vector_type(2)));  // -> v_pk_* ops

union V16 {                    // one 16-byte chunk = 8 halves = 4 h2
    uint4 u;
    h2 h[4];
};
union V8 {                     // 8-byte chunk = 4 halves = 2 h2
    uint2 u;
    h2 h[2];
};

__device__ __forceinline__ float fast_tanh(float x) {
    float e = __expf(2.0f * x);
    return fmaf(-2.0f, __builtin_amdgcn_rcpf(e + 1.0f), 1.0f);
}
__device__ __forceinline__ unsigned packh(float a, float b) {
    h2 v;
    v[0] = (h1)a;
    v[1] = (h1)b;
    return __builtin_bit_cast(unsigned, v);
}
__device__ __forceinline__ h2 ash2(unsigned u) { return __builtin_bit_cast(h2, u); }
__device__ __forceinline__ h2 pkmax0(h2 v) { return __builtin_elementwise_max(v, (h2)(h1)0.0f); }

// packed-weight layout (uint32 slots) appended to ws after the two slabs:
//  [0..23]  w1pk[i*8+n] = {w1[2n*3+i], w1[(2n+1)*3+i]}
//  [24..31] b1pk[n]     = {b1[2n], b1[2n+1]}
//  [32..39] w2pk[n]     = {w2[2n], w2[2n+1]}
//  [40..103]w3pk[n*8+i] = {w3[2n*8+i], w3[(2n+1)*8+i]}
//  [104..111]w4pk[n]    = {w4[2n], w4[2n+1]}
//  [112..119]b3pk[n]    = {b3[2n], b3[2n+1]}

// ---- transpose+convert + weight packing (unchanged from R1 winner)
__global__ __launch_bounds__(256) void transpose_both(const float* __restrict__ g1,
                                                      const float* __restrict__ g2,
                                                      h1* __restrict__ t1,
                                                      h1* __restrict__ t2,
                                                      unsigned* __restrict__ wpk,
                                                      const float* __restrict__ w1,
                                                      const float* __restrict__ b1,
                                                      const float* __restrict__ w2,
                                                      const float* __restrict__ w3,
                                                      const float* __restrict__ b3,
                                                      const float* __restrict__ w4) {
    int idx = blockIdx.x * 256 + threadIdx.x;  // 1,048,576 total
    if (idx < 524288) {                        // grid1 [b][c][z][y][x] linear read
        int x = idx & 15, y = (idx >> 4) & 15, z = (idx >> 8) & 7;
        int c = (idx >> 11) & 31, b = idx >> 16;
        t1[((((b * 16 + y) * 16 + x) * 8 + z) << 5) + c] = (h1)g1[idx];
    } else if (idx < 966656) {                 // grid2 (8*27*2048 = 442368)
        int j = idx - 524288;
        int x = j & 15, y = (j >> 4) & 15, z = (j >> 8) & 7;
        int r = j >> 11;
        int c = r % 27, b = r / 27;
        t2[((((b * 16 + y) * 16 + x) * 8 + z) << 5) + c] = (h1)g2[j];
    } else {                                   // zero 5 pad channels
        int k = idx - 966656;
        int cell = k / 5, p = k - cell * 5;
        t2[(cell << 5) + 27 + p] = (h1)0.0f;
    }
    if (blockIdx.x == 4095) {
        int t = threadIdx.x;
        if (t < 24) {                          // w1pk
            int i = t >> 3, n = t & 7;
            wpk[t] = packh(w1[2 * n * 3 + i], w1[(2 * n + 1) * 3 + i]);
        } else if (t < 32) {
            int n = t - 24;
            wpk[t] = packh(b1[2 * n], b1[2 * n + 1]);
        } else if (t < 40) {
            int n = t - 32;
            wpk[t] = packh(w2[2 * n], w2[2 * n + 1]);
        } else if (t < 104) {
            int k = t - 40;
            int n = k >> 3, i = k & 7;
            wpk[t] = packh(w3[2 * n * 8 + i], w3[(2 * n + 1) * 8 + i]);
        } else if (t < 112) {
            int n = t - 104;
            wpk[t] = packh(w4[2 * n], w4[2 * n + 1]);
        } else if (t < 120) {
            int n = t - 112;
            wpk[t] = packh(b3[2 * n], b3[2 * n + 1]);
        }
    }
}

// ---- fused pipeline; one block = FOUR consecutive rows, one pixel per thread,
// double-buffered slabs (T14 async-stage): issue row r+1's global loads before
// computing row r; interp+ds_write after compute; one barrier per row.
// (512,6): 24 waves/CU (3 blocks x 8 waves, LDS 3x40KB=120KB), VGPR cap 85.
template <bool TR>
__global__ __launch_bounds__(512, 6) void fused10(
    const float* __restrict__ src,
    const void* __restrict__ g1p,
    const void* __restrict__ g2p,
    const unsigned* __restrict__ wpk,
    const float* __restrict__ w1, const float* __restrict__ b1,
    const float* __restrict__ w2, const float* __restrict__ b2,
    const float* __restrict__ w3, const float* __restrict__ b3,
    const float* __restrict__ w4, const float* __restrict__ b4,
    float* __restrict__ out) {
    __shared__ __align__(16) h1 L1h[2][LSLOTH];
    __shared__ __align__(16) h1 L2h[2][LSLOTH];

    int tid = threadIdx.x;
    int b = blockIdx.x >> 7;
    int h0 = (blockIdx.x & 127) << 2;          // first of 4 rows

    const float* sb0 = src + (size_t)b * 3 * HWSZ;
    float* ob0 = out + (size_t)b * 3 * HWSZ;
    int g = tid & 3, cell = tid >> 2;

    uint4 va, vb, ua, ub;                      // in-flight slab loads
    float s0c, s1c, s2c, s0n, s1n, s2n;        // current / next row src

    auto issue_loads = [&](int r) {
        float fyr = (float)(h0 + r) * (15.0f / 512.0f);
        int y0r = (int)fyr;
        const uint4* p1 = (const uint4*)g1p + ((size_t)b * 16 + y0r) * 512;
        const uint4* p2 = (const uint4*)g2p + ((size_t)b * 16 + y0r) * 512;
        va = p1[tid];
        vb = p1[tid + 512];
        ua = p2[tid];
        ub = p2[tid + 512];
    };
    auto write_slab = [&](int r, int bi) {
        float fyr = (float)(h0 + r) * (15.0f / 512.0f);
        int y0r = (int)fyr;
        h2 wyh = (h2)(h1)(fyr - (float)y0r);
        V16 v0, v1, r0;
        v0.u = va;
        v1.u = vb;
#pragma unroll
        for (int k = 0; k < 4; ++k) r0.h[k] = v0.h[k] + (v1.h[k] - v0.h[k]) * wyh;
        *(uint4*)&L1h[bi][cell * CPADH + 8 * g] = r0.u;
        V16 u0, u1, r1;
        u0.u = ua;
        u1.u = ub;
#pragma unroll
        for (int k = 0; k < 4; ++k) r1.h[k] = u0.h[k] + (u1.h[k] - u0.h[k]) * wyh;
        *(uint4*)&L2h[bi][cell * CPADH + 8 * g] = r1.u;
    };

    if constexpr (TR) {                        // prologue: row 0 src + slab
        const float* sb = sb0 + (size_t)h0 * IMW;
        s0c = sb[tid];
        s1c = sb[HWSZ + tid];
        s2c = sb[2 * HWSZ + tid];
        issue_loads(0);
        write_slab(0, 0);
    }

#pragma unroll
    for (int r = 0; r < ROWS; ++r) {
        int hr = h0 + r;
        if constexpr (TR) {
            if (r < ROWS - 1) {                // prefetch next row (slab + src)
                issue_loads(r + 1);
                const float* sb = sb0 + (size_t)(hr + 1) * IMW;
                s0n = sb[tid];
                s1n = sb[HWSZ + tid];
                s2n = sb[2 * HWSZ + tid];
            }
        } else {
            if (r > 0) __syncthreads();        // prev compute done before overwrite
            float fyr = (float)hr * (15.0f / 512.0f);
            int y0r = (int)fyr;
            float wyr = fyr - (float)y0r;
            const float* g1f = (const float*)g1p;
            const float* g2f = (const float*)g2p;
            for (int t = tid; t < L_CELLS * CH; t += 512) {
                int c = t & 31, cl = t >> 5;
                int z = cl & 7, xj = cl >> 3;
                size_t o0 = ((((size_t)b * 32 + c) * 8 + z) * 16 + y0r) * 16 + xj;
                float v0 = g1f[o0], v1 = g1f[o0 + 16];
                L1h[r & 1][cl * CPADH + c] = (h1)fmaf(wyr, v1 - v0, v0);
            }
            for (int t = tid; t < L_CELLS * CH; t += 512) {
                int c = t & 31, cl = t >> 5;
                int z = cl & 7, xj = cl >> 3;
                float v = 0.0f;
                if (c < 27) {
                    size_t o0 = ((((size_t)b * 27 + c) * 8 + z) * 16 + y0r) * 16 + xj;
                    v = fmaf(wyr, g2f[o0 + 16] - g2f[o0], g2f[o0]);
                }
                L2h[r & 1][cl * CPADH + c] = (h1)v;
            }
            const float* sb = sb0 + (size_t)hr * IMW;
            s0c = sb[tid];
            s1c = sb[HWSZ + tid];
            s2c = sb[2 * HWSZ + tid];
        }
        __syncthreads();                       // slab buf[r&1] visible

        const h1* B1 = L1h[r & 1];
        const h1* B2 = L2h[r & 1];
        float* obase = ob0 + (size_t)hr * IMW;
        int w = tid;

        // ---- guide MLP #1: 3 -> 16 -> 1 ----
        float acc;
        h2 s0h, s1h, s2h;
        if constexpr (TR) {
            s0h = (h2)(h1)s0c;
            s1h = (h2)(h1)s1c;
            s2h = (h2)(h1)s2c;
            h2 A;
#pragma unroll
            for (int n = 0; n < 8; ++n) {
                h2 t = ash2(wpk[24 + n]);
                t += s0h * ash2(wpk[n]);
                t += s1h * ash2(wpk[8 + n]);
                t += s2h * ash2(wpk[16 + n]);
                t = pkmax0(t);
                if (n == 0) A = t * ash2(wpk[32]);
                else        A += t * ash2(wpk[32 + n]);
            }
            acc = b2[0] + (float)A[0] + (float)A[1];
        } else {
            acc = b2[0];
#pragma unroll
            for (int j = 0; j < 16; ++j) {
                float t = fmaf(w1[j * 3 + 0], s0c,
                          fmaf(w1[j * 3 + 1], s1c,
                          fmaf(w1[j * 3 + 2], s2c, b1[j])));
                acc = fmaf(w2[j], fmaxf(t, 0.0f), acc);
            }
        }
        float fz = fmaf(fast_tanh(acc), 3.5f, 3.5f);
        fz = fminf(fmaxf(fz, 0.0f), 7.0f);
        int z0 = min((int)fz, 6);
        float wz = fz - (float)z0;

        float fx = (float)w * (15.0f / 512.0f);
        int x0 = (int)fx;
        float wx = fx - (float)x0;
        int a00 = (x0 * 8 + z0) * CPADH;

        float w11v = wx * wz;
        float w10v = wx - w11v;
        float w01v = wz - w11v;
        float w00v = 1.0f - wx - wz + w11v;
        h2 W00 = (h2)(h1)w00v, W01 = (h2)(h1)w01v, W10 = (h2)(h1)w10v, W11 = (h2)(h1)w11v;

        // ---- slice 1: bilinear (x,z) over 32 ch ----
        const uint4* p00 = (const uint4*)&B1[a00];
        const uint4* p01 = (const uint4*)&B1[a00 + CPADH];
        const uint4* p10 = (const uint4*)&B1[a00 + 8 * CPADH];
        const uint4* p11 = (const uint4*)&B1[a00 + 9 * CPADH];
        h2 c1h[16];   // pair m holds channels (2m, 2m+1); channel c = i*8+o
#pragma unroll
        for (int j = 0; j < 4; ++j) {
            V16 A, B, C, D;
            A.u = p00[j];
            B.u = p01[j];
            C.u = p10[j];
            D.u = p11[j];
#pragma unroll
            for (int k = 0; k < 4; ++k)
                c1h[j * 4 + k] = A.h[k] * W00 + B.h[k] * W01 + C.h[k] * W10 + D.h[k] * W11;
        }

        // ---- affine #1: hidden = relu(coeff1 * src) ----
        h2 hidh[4];
        float hidf[8];
        if constexpr (TR) {
#pragma unroll
            for (int n = 0; n < 4; ++n) {
                h2 t = c1h[12 + n];
                t += c1h[n] * s0h;
                t += c1h[4 + n] * s1h;
                t += c1h[8 + n] * s2h;
                hidh[n] = pkmax0(t);
            }
        } else {
#pragma unroll
            for (int o = 0; o < 8; ++o) {
                float t = fmaf((float)c1h[o >> 1][o & 1], s0c,
                          fmaf((float)c1h[(8 + o) >> 1][o & 1], s1c,
                          fmaf((float)c1h[(16 + o) >> 1][o & 1], s2c,
                               (float)c1h[(24 + o) >> 1][o & 1])));
                hidf[o] = fmaxf(t, 0.0f);
            }
        }

        // ---- guide MLP #2: 8 -> 16 -> 1 ----
        float acc2;
        if constexpr (TR) {
            h2 hs[8];
#pragma unroll
            for (int n = 0; n < 4; ++n) {
                hs[2 * n]     = (h2)hidh[n][0];
                hs[2 * n + 1] = (h2)hidh[n][1];
            }
            h2 A;
#pragma unroll
            for (int n = 0; n < 8; ++n) {
                h2 t = ash2(wpk[112 + n]);
#pragma unroll
                for (int i = 0; i < 8; ++i) t += hs[i] * ash2(wpk[40 + n * 8 + i]);
                t = pkmax0(t);
                if (n == 0) A = t * ash2(wpk[104]);
                else        A += t * ash2(wpk[104 + n]);
            }
            acc2 = b4[0] + (float)A[0] + (float)A[1];
#pragma unroll
            for (int n = 0; n < 4; ++n) {
                hidf[2 * n]     = (float)hidh[n][0];
                hidf[2 * n + 1] = (float)hidh[n][1];
            }
        } else {
            acc2 = b4[0];
#pragma unroll
            for (int j = 0; j < 16; ++j) {
                float t = b3[j];
#pragma unroll
                for (int i = 0; i < 8; ++i) t = fmaf(w3[j * 8 + i], hidf[i], t);
                acc2 = fmaf(w4[j], fmaxf(t, 0.0f), acc2);
            }
        }
        float fz2 = fmaf(fast_tanh(acc2), 3.5f, 3.5f);
        fz2 = fminf(fmaxf(fz2, 0.0f), 7.0f);
        int z0b = min((int)fz2, 6);
        float wz2 = fz2 - (float)z0b;

        int a00b = (x0 * 8 + z0b) * CPADH;
        float u11 = wx * wz2;
        float u10 = wx - u11;
        float u01 = wz2 - u11;
        float u00 = 1.0f - wx - wz2 + u11;
        h2 U00 = (h2)(h1)u00, U01 = (h2)(h1)u01, U10 = (h2)(h1)u10, U11 = (h2)(h1)u11;

        // ---- slice 2: bilinear (x,z) over 27 ch (+1 pad), 3x b128 + 1x b64 ----
        const uint4* q00 = (const uint4*)&B2[a00b];
        const uint4* q01 = (const uint4*)&B2[a00b + CPADH];
        const uint4* q10 = (const uint4*)&B2[a00b + 8 * CPADH];
        const uint4* q11 = (const uint4*)&B2[a00b + 9 * CPADH];
        h2 c2h[14];
#pragma unroll
        for (int j = 0; j < 3; ++j) {
            V16 A, B, C, D;
            A.u = q00[j];
            B.u = q01[j];
            C.u = q10[j];
            D.u = q11[j];
#pragma unroll
            for (int k = 0; k < 4; ++k)
                c2h[j * 4 + k] = A.h[k] * U00 + B.h[k] * U01 + C.h[k] * U10 + D.h[k] * U11;
        }
        {
            V8 A, B, C, D;
            A.u = *(const uint2*)&B2[a00b + 24];
            B.u = *(const uint2*)&B2[a00b + CPADH + 24];
            C.u = *(const uint2*)&B2[a00b + 8 * CPADH + 24];
            D.u = *(const uint2*)&B2[a00b + 9 * CPADH + 24];
#pragma unroll
            for (int k = 0; k < 2; ++k)
                c2h[12 + k] = A.h[k] * U00 + B.h[k] * U01 + C.h[k] * U10 + D.h[k] * U11;
        }

        // ---- affine #2 (fp32, inline cvts) ----
#pragma unroll
        for (int o = 0; o < 3; ++o) {
            float t = (float)c2h[(24 + o) >> 1][(24 + o) & 1];
#pragma unroll
            for (int i = 0; i < 8; ++i) {
                int c = i * 3 + o;
                t = fmaf((float)c2h[c >> 1][c & 1], hidf[i], t);
            }
            obase[(size_t)o * HWSZ + w] = t;
        }

        // ---- pipeline: finish next row's slab while this row's out drains ----
        if constexpr (TR) {
            if (r < ROWS - 1) {
                write_slab(r + 1, (r + 1) & 1);
                s0c = s0n;
                s1c = s1n;
                s2c = s2n;
            }
        }
    }
}

extern "C" void kernel_launch(void* const* d_in, const int* in_sizes, int n_in,
                              void* d_out, int out_size, void* d_ws, size_t ws_size,
                              hipStream_t stream) {
    const float* src   = (const float*)d_in[0];
    const float* grid1 = (const float*)d_in[1];
    const float* grid2 = (const float*)d_in[2];
    const float* w1 = (const float*)d_in[3];
    const float* b1 = (const float*)d_in[4];
    const float* w2 = (const float*)d_in[5];
    const float* b2 = (const float*)d_in[6];
    const float* w3 = (const float*)d_in[7];
    const float* b3 = (const float*)d_in[8];
    const float* w4 = (const float*)d_in[9];
    const float* b4 = (const float*)d_in[10];
    float* out = (float*)d_out;

    const size_t t_elems = (size_t)BATCH * 2048 * CH;     // 524288 halves each
    const size_t ws_needed = 2 * t_elems * sizeof(h1) + 512;

    const int nblk = BATCH * IMH / ROWS;                  // 1024 (4 rows each)

    if (ws_size >= ws_needed) {
        h1* t1 = (h1*)d_ws;
        h1* t2 = t1 + t_elems;
        unsigned* wpk = (unsigned*)(t2 + t_elems);
        transpose_both<<<4096, 256, 0, stream>>>(grid1, grid2, t1, t2, wpk,
                                                 w1, b1, w2, w3, b3, w4);
        fused10<true><<<nblk, 512, 0, stream>>>(
            src, t1, t2, wpk, w1, b1, w2, b2, w3, b3, w4, b4, out);
    } else {
        fused10<false><<<nblk, 512, 0, stream>>>(
            src, grid1, grid2, nullptr, w1, b1, w2, b2, w3, b3, w4, b4, out);
    }
}

// Round 5
// 118.146 us; speedup vs baseline: 1.0779x; 1.0779x over previous
//
#include <hip/hip_runtime.h>
#include <math.h>

// src (8,3,512,512) f32 | grid1 (8,32,8,16,16) f32 | grid2 (8,27,8,16,16) f32
// out (8,3,512,512) f32
#define BATCH 8
#define IMH 512
#define IMW 512
#define HWSZ (IMH * IMW)
#define CH 32                  // channels per cell in transposed layout (grid2 padded)
#define CPADH 40               // LDS cell stride in halves (80 B: 16B-aligned, 20-bank stride)
#define L_CELLS (16 * 8)       // full row: 16 x-cells * 8 z
#define LSLOTH (L_CELLS * CPADH)   // 5120 halves = 10240 B per slab

typedef _Float16 h1;
typedef _Float16 h2 __attribute__((ext_vector_type(2)));  // -> v_pk_* ops

union V16 {                    // one 16-byte chunk = 8 halves = 4 h2
    uint4 u;
    h2 h[4];
};
union V8 {                     // 8-byte chunk = 4 halves = 2 h2
    uint2 u;
    h2 h[2];
};

__device__ __forceinline__ float fast_tanh(float x) {
    float e = __expf(2.0f * x);
    return fmaf(-2.0f, __builtin_amdgcn_rcpf(e + 1.0f), 1.0f);
}
__device__ __forceinline__ unsigned packh(float a, float b) {
    h2 v;
    v[0] = (h1)a;
    v[1] = (h1)b;
    return __builtin_bit_cast(unsigned, v);
}
__device__ __forceinline__ h2 ash2(unsigned u) { return __builtin_bit_cast(h2, u); }
__device__ __forceinline__ h2 pkmax0(h2 v) { return __builtin_elementwise_max(v, (h2)(h1)0.0f); }

// packed-weight layout (uint32 slots) appended to ws after the two slabs:
//  [0..23]  w1pk[i*8+n] = {w1[2n*3+i], w1[(2n+1)*3+i]}
//  [24..31] b1pk[n]     = {b1[2n], b1[2n+1]}
//  [32..39] w2pk[n]     = {w2[2n], w2[2n+1]}
//  [40..103]w3pk[n*8+i] = {w3[2n*8+i], w3[(2n+1)*8+i]}
//  [104..111]w4pk[n]    = {w4[2n], w4[2n+1]}
//  [112..119]b3pk[n]    = {b3[2n], b3[2n+1]}

// ---- LDS-tiled transpose+convert + weight packing.
// One block per (b,y): reads land as contiguous 64B segments (4/wave), writes
// are fully-coalesced 16B/lane. Replaces the scattered-2B-write transpose
// (~3us -> ~1.2us predicted). Output layout identical to previous version.
__global__ __launch_bounds__(256) void transpose_tiled(const float* __restrict__ g1,
                                                       const float* __restrict__ g2,
                                                       h1* __restrict__ t1,
                                                       h1* __restrict__ t2,
                                                       unsigned* __restrict__ wpk,
                                                       const float* __restrict__ w1,
                                                       const float* __restrict__ b1,
                                                       const float* __restrict__ w2,
                                                       const float* __restrict__ w3,
                                                       const float* __restrict__ b3,
                                                       const float* __restrict__ w4) {
    __shared__ float S1[4096];   // [c][z][x] for this (b,y): c*128 + z*16 + x
    __shared__ float S2[3456];   // 27 channels

    int tid = threadIdx.x;
    int y = blockIdx.x & 15;
    int b = blockIdx.x >> 4;

    if (blockIdx.x == 0) {       // weight packing (independent of tile work)
        int t = tid;
        if (t < 24) {
            int i = t >> 3, n = t & 7;
            wpk[t] = packh(w1[2 * n * 3 + i], w1[(2 * n + 1) * 3 + i]);
        } else if (t < 32) {
            int n = t - 24;
            wpk[t] = packh(b1[2 * n], b1[2 * n + 1]);
        } else if (t < 40) {
            int n = t - 32;
            wpk[t] = packh(w2[2 * n], w2[2 * n + 1]);
        } else if (t < 104) {
            int k = t - 40;
            int n = k >> 3, i = k & 7;
            wpk[t] = packh(w3[2 * n * 8 + i], w3[(2 * n + 1) * 8 + i]);
        } else if (t < 112) {
            int n = t - 104;
            wpk[t] = packh(w4[2 * n], w4[2 * n + 1]);
        } else if (t < 120) {
            int n = t - 112;
            wpk[t] = packh(b3[2 * n], b3[2 * n + 1]);
        }
    }

    // ---- read phase: idx = c*128 + z*16 + x; input addr = base + c*2048 + z*256 + x
    {
        size_t g1o = (size_t)b * 65536 + y * 16;     // b*32*8*256 + y*16
#pragma unroll
        for (int j = 0; j < 16; ++j) {
            int idx = j * 256 + tid;
            int c = idx >> 7, z = (idx >> 4) & 7, x = idx & 15;
            S1[idx] = g1[g1o + (size_t)c * 2048 + z * 256 + x];
        }
        size_t g2o = (size_t)b * 55296 + y * 16;     // b*27*8*256 + y*16
#pragma unroll
        for (int j = 0; j < 14; ++j) {
            int idx = j * 256 + tid;
            if (idx < 3456) {
                int c = idx >> 7, z = (idx >> 4) & 7, x = idx & 15;
                S2[idx] = g2[g2o + (size_t)c * 2048 + z * 256 + x];
            }
        }
    }
    __syncthreads();

    // ---- write phase: 512 16B-chunks per slab; chunk o -> cell=o>>2, c0=(o&3)*8
    // out half-offset = (b*16+y)*4096 + o*8  (fully coalesced)
    size_t obase = ((size_t)b * 16 + y) * 4096;
#pragma unroll
    for (int j = 0; j < 2; ++j) {
        int o = j * 256 + tid;
        int cell = o >> 2, c0 = (o & 3) * 8;
        int x = cell >> 3, z = cell & 7;
        V16 r;
#pragma unroll
        for (int m = 0; m < 4; ++m) {
            r.h[m][0] = (h1)S1[(c0 + 2 * m) * 128 + z * 16 + x];
            r.h[m][1] = (h1)S1[(c0 + 2 * m + 1) * 128 + z * 16 + x];
        }
        *(uint4*)&t1[obase + (size_t)o * 8] = r.u;
    }
#pragma unroll
    for (int j = 0; j < 2; ++j) {
        int o = j * 256 + tid;
        int cell = o >> 2, c0 = (o & 3) * 8;
        int x = cell >> 3, z = cell & 7;
        V16 r;
#pragma unroll
        for (int m = 0; m < 4; ++m) {
            int ca = c0 + 2 * m, cb = c0 + 2 * m + 1;
            float fa = (ca < 27) ? S2[ca * 128 + z * 16 + x] : 0.0f;
            float fb = (cb < 27) ? S2[cb * 128 + z * 16 + x] : 0.0f;
            r.h[m][0] = (h1)fa;
            r.h[m][1] = (h1)fb;
        }
        *(uint4*)&t2[obase + (size_t)o * 8] = r.u;
    }
}

// ---- fused pipeline; one block = one full row (512 pixels), ONE pixel per thread.
// EXACT revert to the R1 winner (118.9 us total): (512,6), 24 waves/CU.
// R2/R3/R4 established: occupancy 24->32 = 0, half-row = -4, 4-row pipeline = -8.
template <bool TR>
__global__ __launch_bounds__(512, 6) void fused7(
    const float* __restrict__ src,
    const void* __restrict__ g1p,
    const void* __restrict__ g2p,
    const unsigned* __restrict__ wpk,
    const float* __restrict__ w1, const float* __restrict__ b1,
    const float* __restrict__ w2, const float* __restrict__ b2,
    const float* __restrict__ w3, const float* __restrict__ b3,
    const float* __restrict__ w4, const float* __restrict__ b4,
    float* __restrict__ out) {
    __shared__ __align__(16) h1 L1h[LSLOTH];
    __shared__ __align__(16) h1 L2h[LSLOTH];

    int tid = threadIdx.x;
    int h = blockIdx.x & 511;
    int b = blockIdx.x >> 9;

    float fy = (float)h * (15.0f / 512.0f);
    int y0 = (int)fy;
    float wy = fy - (float)y0;

    const float* sbase = src + (size_t)b * 3 * HWSZ + (size_t)h * IMW;
    float s0 = sbase[tid];
    float s1 = sbase[HWSZ + tid];
    float s2 = sbase[2 * HWSZ + tid];

    // ---------------- stage y-interpolated fp16 slabs into LDS ----------------
    if (TR) {
        // exactly 512 chunk-tasks per slab, 512 threads: one task each
        h2 wyh = (h2)(h1)wy;
        const uint4* p1 = (const uint4*)g1p + ((size_t)b * 16 + y0) * 512;
        const uint4* p2 = (const uint4*)g2p + ((size_t)b * 16 + y0) * 512;
        int g = tid & 3, cell = tid >> 2;
        V16 v0, v1, r0;
        v0.u = p1[tid];
        v1.u = p1[tid + 512];
#pragma unroll
        for (int k = 0; k < 4; ++k) r0.h[k] = v0.h[k] + (v1.h[k] - v0.h[k]) * wyh;
        *(uint4*)&L1h[cell * CPADH + 8 * g] = r0.u;
        V16 u0, u1, r1;
        u0.u = p2[tid];
        u1.u = p2[tid + 512];
#pragma unroll
        for (int k = 0; k < 4; ++k) r1.h[k] = u0.h[k] + (u1.h[k] - u0.h[k]) * wyh;
        *(uint4*)&L2h[cell * CPADH + 8 * g] = r1.u;
    } else {
        const float* g1f = (const float*)g1p;
        const float* g2f = (const float*)g2p;
        for (int t = tid; t < L_CELLS * CH; t += 512) {
            int c = t & 31, cell = t >> 5;
            int z = cell & 7, xj = cell >> 3;
            size_t o0 = ((((size_t)b * 32 + c) * 8 + z) * 16 + y0) * 16 + xj;
            float v0 = g1f[o0], v1 = g1f[o0 + 16];
            L1h[cell * CPADH + c] = (h1)fmaf(wy, v1 - v0, v0);
        }
        for (int t = tid; t < L_CELLS * CH; t += 512) {
            int c = t & 31, cell = t >> 5;
            int z = cell & 7, xj = cell >> 3;
            float v = 0.0f;
            if (c < 27) {
                size_t o0 = ((((size_t)b * 27 + c) * 8 + z) * 16 + y0) * 16 + xj;
                v = fmaf(wy, g2f[o0 + 16] - g2f[o0], g2f[o0]);
            }
            L2h[cell * CPADH + c] = (h1)v;
        }
    }
    __syncthreads();

    float* obase = out + (size_t)b * 3 * HWSZ + (size_t)h * IMW;
    int w = tid;

    // ---- guide MLP #1: 3 -> 16 -> 1 ----
    float acc;
    h2 s0h, s1h, s2h;
    if constexpr (TR) {
        s0h = (h2)(h1)s0;
        s1h = (h2)(h1)s1;
        s2h = (h2)(h1)s2;
        h2 A;
#pragma unroll
        for (int n = 0; n < 8; ++n) {
            h2 t = ash2(wpk[24 + n]);
            t += s0h * ash2(wpk[n]);
            t += s1h * ash2(wpk[8 + n]);
            t += s2h * ash2(wpk[16 + n]);
            t = pkmax0(t);
            if (n == 0) A = t * ash2(wpk[32]);
            else        A += t * ash2(wpk[32 + n]);
        }
        acc = b2[0] + (float)A[0] + (float)A[1];
    } else {
        acc = b2[0];
#pragma unroll
        for (int j = 0; j < 16; ++j) {
            float t = fmaf(w1[j * 3 + 0], s0,
                      fmaf(w1[j * 3 + 1], s1,
                      fmaf(w1[j * 3 + 2], s2, b1[j])));
            acc = fmaf(w2[j], fmaxf(t, 0.0f), acc);
        }
    }
    float fz = fmaf(fast_tanh(acc), 3.5f, 3.5f);
    fz = fminf(fmaxf(fz, 0.0f), 7.0f);
    int z0 = min((int)fz, 6);
    float wz = fz - (float)z0;

    float fx = (float)w * (15.0f / 512.0f);
    int x0 = (int)fx;
    float wx = fx - (float)x0;
    int a00 = (x0 * 8 + z0) * CPADH;

    float w11v = wx * wz;
    float w10v = wx - w11v;
    float w01v = wz - w11v;
    float w00v = 1.0f - wx - wz + w11v;
    h2 W00 = (h2)(h1)w00v, W01 = (h2)(h1)w01v, W10 = (h2)(h1)w10v, W11 = (h2)(h1)w11v;

    // ---- slice 1: bilinear (x,z) over 32 ch, packed fp16, result stays h2 ----
    const uint4* p00 = (const uint4*)&L1h[a00];
    const uint4* p01 = (const uint4*)&L1h[a00 + CPADH];
    const uint4* p10 = (const uint4*)&L1h[a00 + 8 * CPADH];
    const uint4* p11 = (const uint4*)&L1h[a00 + 9 * CPADH];
    h2 c1h[16];   // pair m holds channels (2m, 2m+1); channel c = i*8+o
#pragma unroll
    for (int j = 0; j < 4; ++j) {
        V16 A, B, C, D;
        A.u = p00[j];
        B.u = p01[j];
        C.u = p10[j];
        D.u = p11[j];
#pragma unroll
        for (int k = 0; k < 4; ++k)
            c1h[j * 4 + k] = A.h[k] * W00 + B.h[k] * W01 + C.h[k] * W10 + D.h[k] * W11;
    }

    // ---- affine #1: hidden = relu(coeff1 * src) ----
    h2 hidh[4];
    float hidf[8];
    if constexpr (TR) {
#pragma unroll
        for (int n = 0; n < 4; ++n) {
            h2 t = c1h[12 + n];
            t += c1h[n] * s0h;
            t += c1h[4 + n] * s1h;
            t += c1h[8 + n] * s2h;
            hidh[n] = pkmax0(t);
        }
    } else {
#pragma unroll
        for (int o = 0; o < 8; ++o) {
            float t = fmaf((float)c1h[o >> 1][o & 1], s0,
                      fmaf((float)c1h[(8 + o) >> 1][o & 1], s1,
                      fmaf((float)c1h[(16 + o) >> 1][o & 1], s2,
                           (float)c1h[(24 + o) >> 1][o & 1])));
            hidf[o] = fmaxf(t, 0.0f);
        }
    }

    // ---- guide MLP #2: 8 -> 16 -> 1 ----
    float acc2;
    if constexpr (TR) {
        h2 hs[8];
#pragma unroll
        for (int n = 0; n < 4; ++n) {
            hs[2 * n]     = (h2)hidh[n][0];
            hs[2 * n + 1] = (h2)hidh[n][1];
        }
        h2 A;
#pragma unroll
        for (int n = 0; n < 8; ++n) {
            h2 t = ash2(wpk[112 + n]);
#pragma unroll
            for (int i = 0; i < 8; ++i) t += hs[i] * ash2(wpk[40 + n * 8 + i]);
            t = pkmax0(t);
            if (n == 0) A = t * ash2(wpk[104]);
            else        A += t * ash2(wpk[104 + n]);
        }
        acc2 = b4[0] + (float)A[0] + (float)A[1];
        // derive f32 hidden AFTER MLP2 (keeps MLP2-region live set small)
#pragma unroll
        for (int n = 0; n < 4; ++n) {
            hidf[2 * n]     = (float)hidh[n][0];
            hidf[2 * n + 1] = (float)hidh[n][1];
        }
    } else {
        acc2 = b4[0];
#pragma unroll
        for (int j = 0; j < 16; ++j) {
            float t = b3[j];
#pragma unroll
            for (int i = 0; i < 8; ++i) t = fmaf(w3[j * 8 + i], hidf[i], t);
            acc2 = fmaf(w4[j], fmaxf(t, 0.0f), acc2);
        }
    }
    float fz2 = fmaf(fast_tanh(acc2), 3.5f, 3.5f);
    fz2 = fminf(fmaxf(fz2, 0.0f), 7.0f);
    int z0b = min((int)fz2, 6);
    float wz2 = fz2 - (float)z0b;

    int a00b = (x0 * 8 + z0b) * CPADH;
    float u11 = wx * wz2;
    float u10 = wx - u11;
    float u01 = wz2 - u11;
    float u00 = 1.0f - wx - wz2 + u11;
    h2 U00 = (h2)(h1)u00, U01 = (h2)(h1)u01, U10 = (h2)(h1)u10, U11 = (h2)(h1)u11;

    // ---- slice 2: bilinear (x,z) over 27 ch (+1 pad), 3x b128 + 1x b64 per tap ----
    const uint4* q00 = (const uint4*)&L2h[a00b];
    const uint4* q01 = (const uint4*)&L2h[a00b + CPADH];
    const uint4* q10 = (const uint4*)&L2h[a00b + 8 * CPADH];
    const uint4* q11 = (const uint4*)&L2h[a00b + 9 * CPADH];
    h2 c2h[14];
#pragma unroll
    for (int j = 0; j < 3; ++j) {
        V16 A, B, C, D;
        A.u = q00[j];
        B.u = q01[j];
        C.u = q10[j];
        D.u = q11[j];
#pragma unroll
        for (int k = 0; k < 4; ++k)
            c2h[j * 4 + k] = A.h[k] * U00 + B.h[k] * U01 + C.h[k] * U10 + D.h[k] * U11;
    }
    {
        V8 A, B, C, D;
        A.u = *(const uint2*)&L2h[a00b + 24];
        B.u = *(const uint2*)&L2h[a00b + CPADH + 24];
        C.u = *(const uint2*)&L2h[a00b + 8 * CPADH + 24];
        D.u = *(const uint2*)&L2h[a00b + 9 * CPADH + 24];
#pragma unroll
        for (int k = 0; k < 2; ++k)
            c2h[12 + k] = A.h[k] * U00 + B.h[k] * U01 + C.h[k] * U10 + D.h[k] * U11;
    }

    // ---- affine #2 (fp32, inline cvts) ----
#pragma unroll
    for (int o = 0; o < 3; ++o) {
        float t = (float)c2h[(24 + o) >> 1][(24 + o) & 1];
#pragma unroll
        for (int i = 0; i < 8; ++i) {
            int c = i * 3 + o;
            t = fmaf((float)c2h[c >> 1][c & 1], hidf[i], t);
        }
        obase[(size_t)o * HWSZ + w] = t;
    }
}

extern "C" void kernel_launch(void* const* d_in, const int* in_sizes, int n_in,
                              void* d_out, int out_size, void* d_ws, size_t ws_size,
                              hipStream_t stream) {
    const float* src   = (const float*)d_in[0];
    const float* grid1 = (const float*)d_in[1];
    const float* grid2 = (const float*)d_in[2];
    const float* w1 = (const float*)d_in[3];
    const float* b1 = (const float*)d_in[4];
    const float* w2 = (const float*)d_in[5];
    const float* b2 = (const float*)d_in[6];
    const float* w3 = (const float*)d_in[7];
    const float* b3 = (const float*)d_in[8];
    const float* w4 = (const float*)d_in[9];
    const float* b4 = (const float*)d_in[10];
    float* out = (float*)d_out;

    const size_t t_elems = (size_t)BATCH * 2048 * CH;     // 524288 halves each
    const size_t ws_needed = 2 * t_elems * sizeof(h1) + 512;

    const int nblk = BATCH * IMH;                         // 4096 (one row each)

    if (ws_size >= ws_needed) {
        h1* t1 = (h1*)d_ws;
        h1* t2 = t1 + t_elems;
        unsigned* wpk = (unsigned*)(t2 + t_elems);
        transpose_tiled<<<128, 256, 0, stream>>>(grid1, grid2, t1, t2, wpk,
                                                 w1, b1, w2, w3, b3, w4);
        fused7<true><<<nblk, 512, 0, stream>>>(
            src, t1, t2, wpk, w1, b1, w2, b2, w3, b3, w4, b4, out);
    } else {
        fused7<false><<<nblk, 512, 0, stream>>>(
            src, grid1, grid2, nullptr, w1, b1, w2, b2, w3, b3, w4, b4, out);
    }
}